// Round 18
// baseline (197.425 us; speedup 1.0000x reference)
//
#include <hip/hip_runtime.h>
#include <hip/hip_bf16.h>

#define EMBED 1024
#define WINDOW 512
#define NROWS 16384  // 4 * 4096

typedef __attribute__((ext_vector_type(4))) float f32x4;
typedef __bf16 bf16x8 __attribute__((ext_vector_type(8)));

#define GLDS(g, l)                                                        \
  __builtin_amdgcn_global_load_lds(                                       \
      (const __attribute__((address_space(1))) void*)(const void*)(g),    \
      (__attribute__((address_space(3))) void*)(void*)(l), 16, 0, 0)

static __device__ __forceinline__ unsigned bfb(float v) {
  return (unsigned)__builtin_bit_cast(unsigned short, (__bf16)v);
}

// ---------------- prep: fp32 -> bf16 cast, 8 elems/thread ----------------
__global__ __launch_bounds__(256) void cast_bf16_kernel(
    const float* __restrict__ in, __bf16* __restrict__ out, int n8) {
  int i = blockIdx.x * blockDim.x + threadIdx.x;
  if (i >= n8) return;
  const f32x4* p = (const f32x4*)(in + (size_t)i * 8);
  f32x4 a = p[0], b = p[1];
  bf16x8 o = {(__bf16)a[0], (__bf16)a[1], (__bf16)a[2], (__bf16)a[3],
              (__bf16)b[0], (__bf16)b[1], (__bf16)b[2], (__bf16)b[3]};
  *(bf16x8*)(out + (size_t)i * 8) = o;
}

// ------------- prep: MB [512][1024] -> MB^T [1024][512] via LDS ----------
__global__ __launch_bounds__(256) void transpose_mb_lds_kernel(
    const float* __restrict__ mb, __bf16* __restrict__ mbt) {
  __shared__ __bf16 tile[32][33];
  const int tx = threadIdx.x & 7, ty = threadIdx.x >> 3;  // 8 x 32
  const int w0 = (blockIdx.x & 15) * 32;   // 512/32 = 16
  const int d0 = (blockIdx.x >> 4) * 32;   // 1024/32 = 32 -> 512 blocks
  f32x4 v = *(const f32x4*)(mb + (size_t)(w0 + ty) * EMBED + d0 + tx * 4);
#pragma unroll
  for (int j = 0; j < 4; ++j) tile[tx * 4 + j][ty] = (__bf16)v[j];
  __syncthreads();
  unsigned u0 = (bfb((float)tile[ty][tx * 4 + 1]) << 16) |
                bfb((float)tile[ty][tx * 4 + 0]);
  unsigned u1 = (bfb((float)tile[ty][tx * 4 + 3]) << 16) |
                bfb((float)tile[ty][tx * 4 + 2]);
  uint2 w2 = {u0, u1};
  *(uint2*)(mbt + (size_t)(d0 + ty) * WINDOW + w0 + tx * 4) = w2;
}

// ---------------- softmax in-place on S1 rows (512 wide) -----------------
__global__ __launch_bounds__(256) void softmax_kernel(__bf16* __restrict__ s1) {
  const int row = blockIdx.x * 4 + (threadIdx.x >> 6);
  const int lane = threadIdx.x & 63;
  __bf16* p = s1 + (size_t)row * WINDOW + lane * 8;
  bf16x8 v = *(const bf16x8*)p;
  float f[8];
  float mx = -1e30f;
#pragma unroll
  for (int j = 0; j < 8; ++j) {
    f[j] = (float)v[j] * 0.03125f;  // 1/sqrt(1024)
    mx = fmaxf(mx, f[j]);
  }
#pragma unroll
  for (int off = 1; off < 64; off <<= 1) mx = fmaxf(mx, __shfl_xor(mx, off));
  float s = 0.f;
#pragma unroll
  for (int j = 0; j < 8; ++j) {
    f[j] = __expf(f[j] - mx);
    s += f[j];
  }
#pragma unroll
  for (int off = 1; off < 64; off <<= 1) s += __shfl_xor(s, off);
  const float inv = 1.0f / s;
  bf16x8 o;
#pragma unroll
  for (int j = 0; j < 8; ++j) o[j] = (__bf16)(f[j] * inv);
  *(bf16x8*)p = o;
}

// ====== GEMM with A reg-staged from f32 x (kills the x-cast pass) ========
// BM=256, BN=128, BK=64, 512 thr 8 waves (4M x 2N), wave tile 64x64.
// A: per thread 8 x f32x4 loads -> bf16 pack -> 4 x b128 ds_writes into
//    dbuf LDS (64B rows, proven granule involution g ^= row&7).
// B: glds ring-3 (2 glds/wave/tile). 3-deep A ping-pong; derived waits:
//    steady vmcnt(10) [A(t+2)+B(t+1) done], tails vmcnt(2)/vmcnt(0).
// EPI 0: s1 bf16 store (scores).  EPI 1: sigmoid blend (gate).
template <int EPI, int NBN>
__global__ __launch_bounds__(512, 1) void gemm_xA_kernel(
    const float* __restrict__ x, const __bf16* __restrict__ bmat,
    __bf16* __restrict__ s1out, const __bf16* __restrict__ rbb,
    const float* __restrict__ gb, float* __restrict__ out) {
  __shared__ __align__(16) __bf16 ldsA[2][256 * 64];  // 64 KB
  __shared__ __align__(16) __bf16 ldsB[3][128 * 64];  // 48 KB
  const int tid = threadIdx.x, lane = tid & 63, wave = tid >> 6;
  const int bid = blockIdx.x;
  const int xcd = bid & 7;
  const int g = bid >> 3;
  const int bn = g & (NBN - 1);                 // bn inner
  const int bm = xcd * 8 + (g >> (NBN == 4 ? 2 : 3));
  const int row0 = bm * 256, col0 = bn * 128;
  const int warp_m = wave >> 1, warp_n = wave & 1;
  const int fr = lane & 15, fq = lane >> 4;

  // A reg-stage map: row = tid>>1, col half = (tid&1)*32
  const int arow = tid >> 1;
  const int ahalf = tid & 1;
  const float* aSrc = x + (size_t)(row0 + arow) * EMBED + ahalf * 32;

  // B glds map (R16-proven): 8 rows/glds, source granule pre-swizzled
  const int srow = lane >> 3;
  const int sgc = (lane & 7) ^ srow;
  const int wv16 = wave * 16;
  const __bf16* bS = bmat + (size_t)(col0 + wv16 + srow) * EMBED + sgc * 8;

#define ALOAD(dst, t)                                                         \
  {                                                                           \
    _Pragma("unroll") for (int j = 0; j < 8; ++j)                             \
        dst[j] = *(const f32x4*)(aSrc + (t) * 64 + j * 4);                    \
    asm volatile("" ::: "memory");                                            \
  }
#define STG_B(t, slot)                                                        \
  {                                                                           \
    GLDS(bS + (t) * 64, &ldsB[slot][wv16 * 64]);                              \
    GLDS(bS + (size_t)8 * EMBED + (t) * 64, &ldsB[slot][(wv16 + 8) * 64]);    \
  }
#define APACK(src, buf)                                                       \
  {                                                                           \
    _Pragma("unroll") for (int gi = 0; gi < 4; ++gi) {                        \
      uint4 w;                                                                \
      w.x = (bfb(src[2 * gi][1]) << 16) | bfb(src[2 * gi][0]);                \
      w.y = (bfb(src[2 * gi][3]) << 16) | bfb(src[2 * gi][2]);                \
      w.z = (bfb(src[2 * gi + 1][1]) << 16) | bfb(src[2 * gi + 1][0]);        \
      w.w = (bfb(src[2 * gi + 1][3]) << 16) | bfb(src[2 * gi + 1][2]);        \
      *(uint4*)(&ldsA[buf][arow * 64 +                                        \
                           (((ahalf * 4 + gi) ^ (arow & 7)) * 8)]) = w;       \
    }                                                                         \
  }
#define XCOMPUTE(cur, bslot)                                                  \
  {                                                                           \
    const __bf16* As_ = &ldsA[cur][(warp_m * 64 + fr) * 64];                  \
    const __bf16* Bs_ = &ldsB[bslot][(warp_n * 64 + fr) * 64];                \
    _Pragma("unroll") for (int kk = 0; kk < 2; ++kk) {                        \
      const int pg_ = ((kk * 4 + fq) ^ (fr & 7)) * 8;                         \
      bf16x8 af[4], bfv[4];                                                   \
      _Pragma("unroll") for (int m = 0; m < 4; ++m)                           \
          af[m] = *(const bf16x8*)(As_ + m * 16 * 64 + pg_);                  \
      _Pragma("unroll") for (int n = 0; n < 4; ++n)                           \
          bfv[n] = *(const bf16x8*)(Bs_ + n * 16 * 64 + pg_);                 \
      __builtin_amdgcn_s_setprio(1);                                          \
      _Pragma("unroll") for (int m = 0; m < 4; ++m)                           \
          _Pragma("unroll") for (int n = 0; n < 4; ++n)                       \
              acc[m][n] = __builtin_amdgcn_mfma_f32_16x16x32_bf16(            \
                  af[m], bfv[n], acc[m][n], 0, 0, 0);                         \
      __builtin_amdgcn_s_setprio(0);                                          \
    }                                                                         \
  }
#define BARX                                                                  \
  {                                                                           \
    asm volatile("" ::: "memory");                                            \
    __builtin_amdgcn_s_barrier();                                             \
    asm volatile("" ::: "memory");                                            \
  }
// One tile; PK holds A(t+2) to pack; LD receives A(t+3).
#define TBODY(t, PK, LD)                                                      \
  {                                                                           \
    if ((t) + 3 < NT) ALOAD(LD, (t) + 3);                                     \
    if ((t) + 2 < NT) STG_B((t) + 2, ((t) + 2) % 3);                          \
    XCOMPUTE((t) & 1, (t) % 3);                                               \
    BARX;                                                                     \
    if ((t) + 3 < NT) {                                                       \
      asm volatile("s_waitcnt vmcnt(10)" ::: "memory");                       \
    } else if ((t) + 2 < NT) {                                                \
      asm volatile("s_waitcnt vmcnt(2)" ::: "memory");                        \
    } else if ((t) + 1 < NT) {                                                \
      asm volatile("s_waitcnt vmcnt(0)" ::: "memory");                        \
    }                                                                         \
    if ((t) + 2 < NT) {                                                       \
      APACK(PK, (t) & 1);                                                     \
      asm volatile("s_waitcnt lgkmcnt(0)" ::: "memory");                      \
    }                                                                         \
    BARX;                                                                     \
  }

  f32x4 acc[4][4];
#pragma unroll
  for (int m = 0; m < 4; ++m)
#pragma unroll
    for (int n = 0; n < 4; ++n) acc[m][n] = (f32x4){0.f, 0.f, 0.f, 0.f};

  const int NT = 16;  // K = 1024
  f32x4 av[8], nv[8];
  // prologue
  ALOAD(av, 0);
  STG_B(0, 0);
  asm volatile("s_waitcnt vmcnt(2)" ::: "memory");  // A0 done (B0 flying)
  APACK(av, 0);
  ALOAD(av, 1);
  STG_B(1, 1);
  asm volatile("s_waitcnt vmcnt(2)" ::: "memory");  // B0+A1 done (B1 flying)
  APACK(av, 1);
  ALOAD(av, 2);  // A2, packed at t=0
  asm volatile("s_waitcnt lgkmcnt(0)" ::: "memory");
  __builtin_amdgcn_s_barrier();

  for (int t = 0; t < NT; t += 2) {
    TBODY(t, av, nv);
    TBODY(t + 1, nv, av);
  }
#undef TBODY
#undef BARX
#undef XCOMPUTE
#undef APACK
#undef STG_B
#undef ALOAD

  // epilogue
#pragma unroll
  for (int n = 0; n < 4; ++n) {
    const int col = col0 + warp_n * 64 + n * 16 + fr;
    float bias = 0.f;
    if (EPI == 1) bias = gb[col];
#pragma unroll
    for (int m = 0; m < 4; ++m) {
#pragma unroll
      for (int j = 0; j < 4; ++j) {
        const int row = row0 + warp_m * 64 + m * 16 + fq * 4 + j;
        if (EPI == 0) {
          s1out[(size_t)row * WINDOW + col] = (__bf16)acc[m][n][j];
        } else {
          const size_t o = (size_t)row * EMBED + col;
          const float gt = 1.0f / (1.0f + __expf(-(acc[m][n][j] + bias)));
          const float xv = x[o];
          const float rv = (float)rbb[o];
          out[o] = gt * xv + (1.0f - gt) * rv;
        }
      }
    }
  }
}

// ========== retrieved GEMM: rbb = softmax(S1) @ MB  (R16-scores clone) ===
// BM=256, BN=128, K=512 (NT=8), A=s1 (LDA 512), B=mbt (LDB 512), out bf16.
__global__ __launch_bounds__(512, 1) void gemm_retr_kernel(
    const __bf16* __restrict__ s1, const __bf16* __restrict__ mbt,
    __bf16* __restrict__ rbb) {
  __shared__ __align__(16) __bf16 ldsA[3][256 * 64];
  __shared__ __align__(16) __bf16 ldsB[3][128 * 64];
  const int tid = threadIdx.x;
  const int lane = tid & 63;
  const int wave = tid >> 6;
  const int bid = blockIdx.x;            // 512 blocks
  const int xcd = bid & 7;
  const int g = bid >> 3;                // 0..63
  const int bm = xcd * 8 + (g >> 3);     // bn inner
  const int bn = g & 7;
  const int row0 = bm * 256;
  const int col0 = bn * 128;
  const int warp_m = wave >> 1;
  const int warp_n = wave & 1;
  const int srow = lane >> 3;
  const int sgc = (lane & 7) ^ srow;
  const int wv32 = wave * 32;
  const int wv16 = wave * 16;
  const int fr = lane & 15;
  const int fq = lane >> 4;

  const __bf16* aS = s1 + (size_t)(row0 + wv32 + srow) * WINDOW + sgc * 8;
  const __bf16* bS = mbt + (size_t)(col0 + wv16 + srow) * WINDOW + sgc * 8;

#define STAGE_R1(vt, buf)                                                     \
  {                                                                           \
    const int k0_ = (vt)*64;                                                  \
    _Pragma("unroll") for (int c = 0; c < 2; ++c)                             \
        GLDS(aS + (size_t)c * 8 * WINDOW + k0_,                               \
             &ldsA[buf][(wv32 + c * 8) * 64]);                                \
    GLDS(bS + k0_, &ldsB[buf][wv16 * 64]);                                    \
  }
#define STAGE_R2(vt, buf)                                                     \
  {                                                                           \
    const int k0_ = (vt)*64;                                                  \
    _Pragma("unroll") for (int c = 2; c < 4; ++c)                             \
        GLDS(aS + (size_t)c * 8 * WINDOW + k0_,                               \
             &ldsA[buf][(wv32 + c * 8) * 64]);                                \
    GLDS(bS + (size_t)8 * WINDOW + k0_, &ldsB[buf][(wv16 + 8) * 64]);         \
  }
#define RLOADFRAGS(cb, kk)                                                    \
  {                                                                           \
    const __bf16* As_ = &ldsA[cb][(warp_m * 64 + fr) * 64];                   \
    const __bf16* Bs_ = &ldsB[cb][(warp_n * 64 + fr) * 64];                   \
    const int pg_ = (((kk)*4 + fq) ^ (fr & 7)) * 8;                           \
    _Pragma("unroll") for (int m = 0; m < 4; ++m)                             \
        af[m] = *(const bf16x8*)(As_ + m * 16 * 64 + pg_);                    \
    _Pragma("unroll") for (int n = 0; n < 4; ++n)                             \
        bfv[n] = *(const bf16x8*)(Bs_ + n * 16 * 64 + pg_);                   \
  }
#define RMFMA16                                                               \
  {                                                                           \
    __builtin_amdgcn_s_barrier();                                             \
    asm volatile("s_waitcnt lgkmcnt(0)" ::: "memory");                        \
    __builtin_amdgcn_s_setprio(1);                                            \
    _Pragma("unroll") for (int m = 0; m < 4; ++m)                             \
        _Pragma("unroll") for (int n = 0; n < 4; ++n)                         \
            acc[m][n] = __builtin_amdgcn_mfma_f32_16x16x32_bf16(              \
                af[m], bfv[n], acc[m][n], 0, 0, 0);                           \
    __builtin_amdgcn_s_setprio(0);                                            \
    __builtin_amdgcn_s_barrier();                                             \
  }

  f32x4 acc[4][4];
#pragma unroll
  for (int m = 0; m < 4; ++m)
#pragma unroll
    for (int n = 0; n < 4; ++n) acc[m][n] = (f32x4){0.f, 0.f, 0.f, 0.f};
  bf16x8 af[4], bfv[4];

  STAGE_R1(0, 0); STAGE_R2(0, 0);
  STAGE_R1(1, 1); STAGE_R2(1, 1);
  asm volatile("s_waitcnt vmcnt(6)" ::: "memory");
  __builtin_amdgcn_s_barrier();

  const int NT = 8;  // K = 512
  for (int vt = 0; vt < NT; ++vt) {
    const int cb = vt % 3;
    const int nb = (vt + 2) % 3;
    RLOADFRAGS(cb, 0);
    if (vt + 2 < NT) STAGE_R1(vt + 2, nb);
    RMFMA16;
    RLOADFRAGS(cb, 1);
    if (vt + 2 < NT) STAGE_R2(vt + 2, nb);
    if (vt < NT - 2) {
      asm volatile("s_waitcnt vmcnt(6)" ::: "memory");
    } else if (vt == NT - 2) {
      asm volatile("s_waitcnt vmcnt(0)" ::: "memory");
    }
    RMFMA16;
  }
#undef STAGE_R1
#undef STAGE_R2
#undef RLOADFRAGS
#undef RMFMA16

#pragma unroll
  for (int n = 0; n < 4; ++n) {
    const int col = col0 + warp_n * 64 + n * 16 + fr;
#pragma unroll
    for (int m = 0; m < 4; ++m)
#pragma unroll
      for (int j = 0; j < 4; ++j) {
        const int row = row0 + warp_m * 64 + m * 16 + fq * 4 + j;
        rbb[(size_t)row * EMBED + col] = (__bf16)acc[m][n][j];
      }
  }
}

extern "C" void kernel_launch(void* const* d_in, const int* in_sizes, int n_in,
                              void* d_out, int out_size, void* d_ws,
                              size_t ws_size, hipStream_t stream) {
  const float* x = (const float*)d_in[0];
  const float* mb = (const float*)d_in[1];
  const float* gw = (const float*)d_in[2];
  const float* gb = (const float*)d_in[3];
  float* out = (float*)d_out;

  char* ws = (char*)d_ws;
  __bf16* rbb = (__bf16*)(ws);                  // 16384*1024*2 = 33,554,432
  __bf16* mbb = (__bf16*)(ws + 33554432);       // 512*1024*2  =  1,048,576
  __bf16* mbt = (__bf16*)(ws + 34603008);       // 1024*512*2  =  1,048,576
  __bf16* gwb = (__bf16*)(ws + 35651584);       // 1024*1024*2 =  2,097,152
  __bf16* s1 = (__bf16*)(ws + 37748736);        // 16384*512*2 = 16,777,216
  // total 54,525,952 bytes (same footprint as before; xb -> rbb)

  cast_bf16_kernel<<<256, 256, 0, stream>>>(mb, mbb, 65536);
  cast_bf16_kernel<<<512, 256, 0, stream>>>(gw, gwb, 131072);
  transpose_mb_lds_kernel<<<512, 256, 0, stream>>>(mb, mbt);
  // scores: s1 = (x @ mbb^T), A reg-staged from f32 x (no x-cast pass)
  gemm_xA_kernel<0, 4><<<256, 512, 0, stream>>>(x, mbb, s1, nullptr, gb, out);
  softmax_kernel<<<4096, 256, 0, stream>>>(s1);
  // retrieved: rbb = softmax(s1) @ MB  (bf16)
  gemm_retr_kernel<<<512, 512, 0, stream>>>(s1, mbt, rbb);
  // gate + blend: out = sigmoid(x@gw^T + gb) * x + (1-.)*rbb
  gemm_xA_kernel<1, 8><<<512, 512, 0, stream>>>(x, gwb, nullptr, rbb, gb, out);
}

// Round 19
// 133.115 us; speedup vs baseline: 1.4831x; 1.4831x over previous
//
#include <hip/hip_runtime.h>
#include <hip/hip_bf16.h>

#define EMBED 1024
#define WINDOW 512
#define NROWS 16384  // 4 * 4096

typedef __attribute__((ext_vector_type(4))) float f32x4;
typedef __bf16 bf16x8 __attribute__((ext_vector_type(8)));

#define GLDS(g, l)                                                        \
  __builtin_amdgcn_global_load_lds(                                       \
      (const __attribute__((address_space(1))) void*)(const void*)(g),    \
      (__attribute__((address_space(3))) void*)(void*)(l), 16, 0, 0)

static __device__ __forceinline__ unsigned bfb(float v) {
  return (unsigned)__builtin_bit_cast(unsigned short, (__bf16)v);
}

// ---------------- prep: fp32 -> bf16 cast, 8 elems/thread ----------------
__global__ __launch_bounds__(256) void cast_bf16_kernel(
    const float* __restrict__ in, __bf16* __restrict__ out, int n8) {
  int i = blockIdx.x * blockDim.x + threadIdx.x;
  if (i >= n8) return;
  const f32x4* p = (const f32x4*)(in + (size_t)i * 8);
  f32x4 a = p[0], b = p[1];
  bf16x8 o = {(__bf16)a[0], (__bf16)a[1], (__bf16)a[2], (__bf16)a[3],
              (__bf16)b[0], (__bf16)b[1], (__bf16)b[2], (__bf16)b[3]};
  *(bf16x8*)(out + (size_t)i * 8) = o;
}

// ------------- prep: MB [512][1024] -> MB^T [1024][512] via LDS ----------
__global__ __launch_bounds__(256) void transpose_mb_lds_kernel(
    const float* __restrict__ mb, __bf16* __restrict__ mbt) {
  __shared__ __bf16 tile[32][33];
  const int tx = threadIdx.x & 7, ty = threadIdx.x >> 3;  // 8 x 32
  const int w0 = (blockIdx.x & 15) * 32;   // 512/32 = 16
  const int d0 = (blockIdx.x >> 4) * 32;   // 1024/32 = 32 -> 512 blocks
  f32x4 v = *(const f32x4*)(mb + (size_t)(w0 + ty) * EMBED + d0 + tx * 4);
#pragma unroll
  for (int j = 0; j < 4; ++j) tile[tx * 4 + j][ty] = (__bf16)v[j];
  __syncthreads();
  unsigned u0 = (bfb((float)tile[ty][tx * 4 + 1]) << 16) |
                bfb((float)tile[ty][tx * 4 + 0]);
  unsigned u1 = (bfb((float)tile[ty][tx * 4 + 3]) << 16) |
                bfb((float)tile[ty][tx * 4 + 2]);
  uint2 w2 = {u0, u1};
  *(uint2*)(mbt + (size_t)(d0 + ty) * WINDOW + w0 + tx * 4) = w2;
}

// ---------------- softmax in-place on S1 rows (512 wide) -----------------
__global__ __launch_bounds__(256) void softmax_kernel(__bf16* __restrict__ s1) {
  const int row = blockIdx.x * 4 + (threadIdx.x >> 6);
  const int lane = threadIdx.x & 63;
  __bf16* p = s1 + (size_t)row * WINDOW + lane * 8;
  bf16x8 v = *(const bf16x8*)p;
  float f[8];
  float mx = -1e30f;
#pragma unroll
  for (int j = 0; j < 8; ++j) {
    f[j] = (float)v[j] * 0.03125f;  // 1/sqrt(1024)
    mx = fmaxf(mx, f[j]);
  }
#pragma unroll
  for (int off = 1; off < 64; off <<= 1) mx = fmaxf(mx, __shfl_xor(mx, off));
  float s = 0.f;
#pragma unroll
  for (int j = 0; j < 8; ++j) {
    f[j] = __expf(f[j] - mx);
    s += f[j];
  }
#pragma unroll
  for (int off = 1; off < 64; off <<= 1) s += __shfl_xor(s, off);
  const float inv = 1.0f / s;
  bf16x8 o;
#pragma unroll
  for (int j = 0; j < 8; ++j) o[j] = (__bf16)(f[j] * inv);
  *(bf16x8*)p = o;
}

// ====== R16-scores-structure GEMM, templated (proven @ ~1 PF eff) ========
// BM=256, BN=128, BK=64, 512 thr 8 waves (4M x 2N), 3-ring LDS,
// counted vmcnt(6), proven 64B-row granule involution (0 conflicts).
// EPI 0: bf16 store to outb (stride OSTR).
// EPI 1: g = sigmoid(acc + gb[col]); out = g*xb + (1-g)*rbb  (f32 out).
template <int NT, int LDA_, int LDB_, int NBN, int EPI, int OSTR>
__global__ __launch_bounds__(512, 2) void gemm_sp_kernel(
    const __bf16* __restrict__ A, const __bf16* __restrict__ B,
    __bf16* __restrict__ outb, const __bf16* __restrict__ xb,
    const __bf16* __restrict__ rbb, const float* __restrict__ gb,
    float* __restrict__ out) {
  __shared__ __align__(16) __bf16 ldsA[3][256 * 64];
  __shared__ __align__(16) __bf16 ldsB[3][128 * 64];
  const int tid = threadIdx.x;
  const int lane = tid & 63;
  const int wave = tid >> 6;
  const int bid = blockIdx.x;
  const int xcd = bid & 7;
  const int idx = bid >> 3;
  const int bn = idx & (NBN - 1);                      // bn inner
  const int bm = xcd * 8 + (idx >> (NBN == 4 ? 2 : 3));
  const int row0 = bm * 256;
  const int col0 = bn * 128;
  const int warp_m = wave >> 1;
  const int warp_n = wave & 1;
  const int srow = lane >> 3;
  const int sgc = (lane & 7) ^ srow;
  const int wv32 = wave * 32;
  const int wv16 = wave * 16;
  const int fr = lane & 15;
  const int fq = lane >> 4;

  const __bf16* aS = A + (size_t)(row0 + wv32 + srow) * LDA_ + sgc * 8;
  const __bf16* bS = B + (size_t)(col0 + wv16 + srow) * LDB_ + sgc * 8;

#define STAGE_P1(vt, buf)                                                     \
  {                                                                           \
    const int k0_ = (vt)*64;                                                  \
    _Pragma("unroll") for (int c = 0; c < 2; ++c)                             \
        GLDS(aS + (size_t)c * 8 * LDA_ + k0_,                                 \
             &ldsA[buf][(wv32 + c * 8) * 64]);                                \
    GLDS(bS + k0_, &ldsB[buf][wv16 * 64]);                                    \
  }
#define STAGE_P2(vt, buf)                                                     \
  {                                                                           \
    const int k0_ = (vt)*64;                                                  \
    _Pragma("unroll") for (int c = 2; c < 4; ++c)                             \
        GLDS(aS + (size_t)c * 8 * LDA_ + k0_,                                 \
             &ldsA[buf][(wv32 + c * 8) * 64]);                                \
    GLDS(bS + (size_t)8 * LDB_ + k0_, &ldsB[buf][(wv16 + 8) * 64]);           \
  }
#define PLOADFRAGS(cb, kk)                                                    \
  {                                                                           \
    const __bf16* As_ = &ldsA[cb][(warp_m * 64 + fr) * 64];                   \
    const __bf16* Bs_ = &ldsB[cb][(warp_n * 64 + fr) * 64];                   \
    const int pg_ = (((kk)*4 + fq) ^ (fr & 7)) * 8;                           \
    _Pragma("unroll") for (int m = 0; m < 4; ++m)                             \
        af[m] = *(const bf16x8*)(As_ + m * 16 * 64 + pg_);                    \
    _Pragma("unroll") for (int n = 0; n < 4; ++n)                             \
        bfv[n] = *(const bf16x8*)(Bs_ + n * 16 * 64 + pg_);                   \
  }
#define PMFMA16                                                               \
  {                                                                           \
    __builtin_amdgcn_s_barrier();                                             \
    asm volatile("s_waitcnt lgkmcnt(0)" ::: "memory");                        \
    __builtin_amdgcn_s_setprio(1);                                            \
    _Pragma("unroll") for (int m = 0; m < 4; ++m)                             \
        _Pragma("unroll") for (int n = 0; n < 4; ++n)                         \
            acc[m][n] = __builtin_amdgcn_mfma_f32_16x16x32_bf16(              \
                af[m], bfv[n], acc[m][n], 0, 0, 0);                           \
    __builtin_amdgcn_s_setprio(0);                                            \
    __builtin_amdgcn_s_barrier();                                             \
  }

  f32x4 acc[4][4];
#pragma unroll
  for (int m = 0; m < 4; ++m)
#pragma unroll
    for (int n = 0; n < 4; ++n) acc[m][n] = (f32x4){0.f, 0.f, 0.f, 0.f};
  bf16x8 af[4], bfv[4];

  STAGE_P1(0, 0); STAGE_P2(0, 0);
  STAGE_P1(1, 1); STAGE_P2(1, 1);
  asm volatile("s_waitcnt vmcnt(6)" ::: "memory");
  __builtin_amdgcn_s_barrier();

  for (int vt = 0; vt < NT; ++vt) {
    const int cb = vt % 3;
    const int nb = (vt + 2) % 3;
    PLOADFRAGS(cb, 0);
    if (vt + 2 < NT) STAGE_P1(vt + 2, nb);
    PMFMA16;
    PLOADFRAGS(cb, 1);
    if (vt + 2 < NT) STAGE_P2(vt + 2, nb);
    if (vt < NT - 2) {
      asm volatile("s_waitcnt vmcnt(6)" ::: "memory");
    } else if (vt == NT - 2) {
      asm volatile("s_waitcnt vmcnt(0)" ::: "memory");
    }
    PMFMA16;
  }
#undef STAGE_P1
#undef STAGE_P2
#undef PLOADFRAGS
#undef PMFMA16

#pragma unroll
  for (int n = 0; n < 4; ++n) {
    const int col = col0 + warp_n * 64 + n * 16 + fr;
    float bias = 0.f;
    if (EPI == 1) bias = gb[col];
#pragma unroll
    for (int m = 0; m < 4; ++m) {
#pragma unroll
      for (int j = 0; j < 4; ++j) {
        const int row = row0 + warp_m * 64 + m * 16 + fq * 4 + j;
        if (EPI == 0) {
          outb[(size_t)row * OSTR + col] = (__bf16)acc[m][n][j];
        } else {
          const size_t o = (size_t)row * EMBED + col;
          const float gt = 1.0f / (1.0f + __expf(-(acc[m][n][j] + bias)));
          out[o] = gt * (float)xb[o] + (1.0f - gt) * (float)rbb[o];
        }
      }
    }
  }
}

// ======= fallback: fused dual GEMM + blend (R16 verbatim, 73 us) =========
__global__ __launch_bounds__(256, 2) void dual_fused128_kernel(
    const __bf16* __restrict__ s1, const __bf16* __restrict__ xb,
    const __bf16* __restrict__ mbt, const __bf16* __restrict__ gwb,
    const float* __restrict__ gb, float* __restrict__ out) {
  __shared__ __align__(16) __bf16 ldsA[2][128 * 64];  // 32 KB
  __shared__ __align__(16) __bf16 ldsB[2][128 * 64];  // 32 KB
  const int tid = threadIdx.x, lane = tid & 63, wave = tid >> 6;
  const int bid = blockIdx.x;
  const int xcd = bid & 7;
  const int g = bid >> 3;                  // 0..127
  const int bm = xcd * 16 + (g >> 3);      // bn inner: A-panel L2 locality
  const int bn = g & 7;
  const int row0 = bm * 128, col0 = bn * 128;
  const int warp_m = wave >> 1, warp_n = wave & 1;  // 2x2 waves, 64x64 tiles
  const int fr = lane & 15, fq = lane >> 4;
  const int srow = lane >> 3;              // 0..7
  const int sgc = (lane & 7) ^ srow;       // pre-swizzled source granule
  const int wv32 = wave * 32;

  const __bf16* aR = s1 + (size_t)(row0 + wv32 + srow) * WINDOW + sgc * 8;
  const __bf16* bR = mbt + (size_t)(col0 + wv32 + srow) * WINDOW + sgc * 8;
  const __bf16* aG = xb + (size_t)(row0 + wv32 + srow) * EMBED + sgc * 8;
  const __bf16* bG = gwb + (size_t)(col0 + wv32 + srow) * EMBED + sgc * 8;

#define STG(vt, buf)                                                          \
  {                                                                           \
    if ((vt) < 8) {                                                           \
      const int k0_ = (vt)*64;                                                \
      _Pragma("unroll") for (int c = 0; c < 4; ++c)                           \
          GLDS(aR + (size_t)c * 8 * WINDOW + k0_,                             \
               &ldsA[buf][(wv32 + c * 8) * 64]);                              \
      _Pragma("unroll") for (int c = 0; c < 4; ++c)                           \
          GLDS(bR + (size_t)c * 8 * WINDOW + k0_,                             \
               &ldsB[buf][(wv32 + c * 8) * 64]);                              \
    } else {                                                                  \
      const int k0_ = ((vt)-8) * 64;                                          \
      _Pragma("unroll") for (int c = 0; c < 4; ++c)                           \
          GLDS(aG + (size_t)c * 8 * EMBED + k0_,                              \
               &ldsA[buf][(wv32 + c * 8) * 64]);                              \
      _Pragma("unroll") for (int c = 0; c < 4; ++c)                           \
          GLDS(bG + (size_t)c * 8 * EMBED + k0_,                              \
               &ldsB[buf][(wv32 + c * 8) * 64]);                              \
    }                                                                         \
  }

#define BARF                                                                  \
  {                                                                           \
    asm volatile("" ::: "memory");                                            \
    __builtin_amdgcn_s_barrier();                                             \
    asm volatile("" ::: "memory");                                            \
  }

#define COMPUTE(ACC, cur)                                                     \
  {                                                                           \
    const __bf16* As_ = &ldsA[cur][(warp_m * 64 + fr) * 64];                  \
    const __bf16* Bs_ = &ldsB[cur][(warp_n * 64 + fr) * 64];                  \
    _Pragma("unroll") for (int kk = 0; kk < 2; ++kk) {                        \
      const int pg_ = ((kk * 4 + fq) ^ (fr & 7)) * 8;                         \
      bf16x8 af[4], bfv[4];                                                   \
      _Pragma("unroll") for (int m = 0; m < 4; ++m)                           \
          af[m] = *(const bf16x8*)(As_ + m * 16 * 64 + pg_);                  \
      _Pragma("unroll") for (int n = 0; n < 4; ++n)                           \
          bfv[n] = *(const bf16x8*)(Bs_ + n * 16 * 64 + pg_);                 \
      __builtin_amdgcn_s_setprio(1);                                          \
      _Pragma("unroll") for (int m = 0; m < 4; ++m)                           \
          _Pragma("unroll") for (int n = 0; n < 4; ++n)                       \
              ACC[m][n] = __builtin_amdgcn_mfma_f32_16x16x32_bf16(            \
                  af[m], bfv[n], ACC[m][n], 0, 0, 0);                         \
      __builtin_amdgcn_s_setprio(0);                                          \
    }                                                                         \
  }

  f32x4 accr[4][4], accg[4][4];
#pragma unroll
  for (int m = 0; m < 4; ++m)
#pragma unroll
    for (int n = 0; n < 4; ++n) {
      accr[m][n] = (f32x4){0.f, 0.f, 0.f, 0.f};
      accg[m][n] = (f32x4){0.f, 0.f, 0.f, 0.f};
    }

  STG(0, 0);
  for (int vt = 0; vt < 8; ++vt) {
    const int cur = vt & 1;
    STG(vt + 1, cur ^ 1);
    asm volatile("s_waitcnt vmcnt(8)" ::: "memory");
    BARF;
    COMPUTE(accr, cur);
    BARF;
  }
  for (int vt = 8; vt < 24; ++vt) {
    const int cur = vt & 1;
    if (vt + 1 < 24) {
      STG(vt + 1, cur ^ 1);
      asm volatile("s_waitcnt vmcnt(8)" ::: "memory");
    } else {
      asm volatile("s_waitcnt vmcnt(0)" ::: "memory");
    }
    BARF;
    COMPUTE(accg, cur);
    BARF;
  }
#undef STG
#undef COMPUTE
#undef BARF

#pragma unroll
  for (int n = 0; n < 4; ++n) {
    const int col = col0 + warp_n * 64 + n * 16 + fr;
    const float bias = gb[col];
#pragma unroll
    for (int m = 0; m < 4; ++m) {
#pragma unroll
      for (int j = 0; j < 4; ++j) {
        const int row = row0 + warp_m * 64 + m * 16 + fq * 4 + j;
        const size_t o = (size_t)row * EMBED + col;
        const float gt = 1.0f / (1.0f + __expf(-(accg[m][n][j] + bias)));
        const float xv = (float)xb[o];
        out[o] = gt * xv + (1.0f - gt) * accr[m][n][j];
      }
    }
  }
}

extern "C" void kernel_launch(void* const* d_in, const int* in_sizes, int n_in,
                              void* d_out, int out_size, void* d_ws,
                              size_t ws_size, hipStream_t stream) {
  const float* x = (const float*)d_in[0];
  const float* mb = (const float*)d_in[1];
  const float* gw = (const float*)d_in[2];
  const float* gb = (const float*)d_in[3];
  float* out = (float*)d_out;

  char* ws = (char*)d_ws;
  __bf16* xb = (__bf16*)(ws);                   // 16384*1024*2 = 33,554,432
  __bf16* mbb = (__bf16*)(ws + 33554432);       // 512*1024*2  =  1,048,576
  __bf16* mbt = (__bf16*)(ws + 34603008);       // 1024*512*2  =  1,048,576
  __bf16* gwb = (__bf16*)(ws + 35651584);       // 1024*1024*2 =  2,097,152
  __bf16* s1 = (__bf16*)(ws + 37748736);        // 16384*512*2 = 16,777,216
  __bf16* rbb = (__bf16*)(ws + 54525952);       // 16384*1024*2 = 33,554,432
  const bool ws_big = ws_size >= 88080384ull;   // needs rbb slot

  cast_bf16_kernel<<<8192, 256, 0, stream>>>(x, xb, 2097152);
  cast_bf16_kernel<<<256, 256, 0, stream>>>(mb, mbb, 65536);
  cast_bf16_kernel<<<512, 256, 0, stream>>>(gw, gwb, 131072);
  transpose_mb_lds_kernel<<<512, 256, 0, stream>>>(mb, mbt);
  // scores: s1 = xb @ mbb^T (bf16), R16-proven structure
  gemm_sp_kernel<16, EMBED, EMBED, 4, 0, WINDOW><<<256, 512, 0, stream>>>(
      xb, mbb, s1, nullptr, nullptr, gb, out);
  softmax_kernel<<<4096, 256, 0, stream>>>(s1);
  if (ws_big) {
    // retrieved: rbb = softmax(s1) @ MB (bf16, stride EMBED)
    gemm_sp_kernel<8, WINDOW, WINDOW, 8, 0, EMBED><<<512, 512, 0, stream>>>(
        s1, mbt, rbb, nullptr, nullptr, gb, out);
    // gate + blend: out = sigmoid(xb@gw^T + gb)*xb + (1-.)*rbb
    gemm_sp_kernel<16, EMBED, EMBED, 8, 1, EMBED><<<512, 512, 0, stream>>>(
        xb, gwb, nullptr, xb, rbb, gb, out);
  } else {
    dual_fused128_kernel<<<1024, 256, 0, stream>>>(s1, xb, mbt, gwb, gb, out);
  }
}

// Round 20
// 116.845 us; speedup vs baseline: 1.6896x; 1.1392x over previous
//
#include <hip/hip_runtime.h>
#include <hip/hip_bf16.h>

#define EMBED 1024
#define WINDOW 512
#define NROWS 16384  // 4 * 4096

typedef __attribute__((ext_vector_type(4))) float f32x4;
typedef __bf16 bf16x8 __attribute__((ext_vector_type(8)));

#define GLDS(g, l)                                                        \
  __builtin_amdgcn_global_load_lds(                                       \
      (const __attribute__((address_space(1))) void*)(const void*)(g),    \
      (__attribute__((address_space(3))) void*)(void*)(l), 16, 0, 0)

static __device__ __forceinline__ unsigned bfb(float v) {
  return (unsigned)__builtin_bit_cast(unsigned short, (__bf16)v);
}

// ---------------- prep: fp32 -> bf16 cast, 8 elems/thread ----------------
__global__ __launch_bounds__(256) void cast_bf16_kernel(
    const float* __restrict__ in, __bf16* __restrict__ out, int n8) {
  int i = blockIdx.x * blockDim.x + threadIdx.x;
  if (i >= n8) return;
  const f32x4* p = (const f32x4*)(in + (size_t)i * 8);
  f32x4 a = p[0], b = p[1];
  bf16x8 o = {(__bf16)a[0], (__bf16)a[1], (__bf16)a[2], (__bf16)a[3],
              (__bf16)b[0], (__bf16)b[1], (__bf16)b[2], (__bf16)b[3]};
  *(bf16x8*)(out + (size_t)i * 8) = o;
}

// ------------- prep: MB [512][1024] -> MB^T [1024][512] via LDS ----------
__global__ __launch_bounds__(256) void transpose_mb_lds_kernel(
    const float* __restrict__ mb, __bf16* __restrict__ mbt) {
  __shared__ __bf16 tile[32][33];
  const int tx = threadIdx.x & 7, ty = threadIdx.x >> 3;  // 8 x 32
  const int w0 = (blockIdx.x & 15) * 32;   // 512/32 = 16
  const int d0 = (blockIdx.x >> 4) * 32;   // 1024/32 = 32 -> 512 blocks
  f32x4 v = *(const f32x4*)(mb + (size_t)(w0 + ty) * EMBED + d0 + tx * 4);
#pragma unroll
  for (int j = 0; j < 4; ++j) tile[tx * 4 + j][ty] = (__bf16)v[j];
  __syncthreads();
  unsigned u0 = (bfb((float)tile[ty][tx * 4 + 1]) << 16) |
                bfb((float)tile[ty][tx * 4 + 0]);
  unsigned u1 = (bfb((float)tile[ty][tx * 4 + 3]) << 16) |
                bfb((float)tile[ty][tx * 4 + 2]);
  uint2 w2 = {u0, u1};
  *(uint2*)(mbt + (size_t)(d0 + ty) * WINDOW + w0 + tx * 4) = w2;
}

// ---------------- softmax in-place on S1 rows (512 wide) -----------------
__global__ __launch_bounds__(256) void softmax_kernel(__bf16* __restrict__ s1) {
  const int row = blockIdx.x * 4 + (threadIdx.x >> 6);
  const int lane = threadIdx.x & 63;
  __bf16* p = s1 + (size_t)row * WINDOW + lane * 8;
  bf16x8 v = *(const bf16x8*)p;
  float f[8];
  float mx = -1e30f;
#pragma unroll
  for (int j = 0; j < 8; ++j) {
    f[j] = (float)v[j] * 0.03125f;  // 1/sqrt(1024)
    mx = fmaxf(mx, f[j]);
  }
#pragma unroll
  for (int off = 1; off < 64; off <<= 1) mx = fmaxf(mx, __shfl_xor(mx, off));
  float s = 0.f;
#pragma unroll
  for (int j = 0; j < 8; ++j) {
    f[j] = __expf(f[j] - mx);
    s += f[j];
  }
#pragma unroll
  for (int off = 1; off < 64; off <<= 1) s += __shfl_xor(s, off);
  const float inv = 1.0f / s;
  bf16x8 o;
#pragma unroll
  for (int j = 0; j < 8; ++j) o[j] = (__bf16)(f[j] * inv);
  *(bf16x8*)p = o;
}

// ---------------- scores kernel (R5 structure, known-good) ---------------
#define SLOADFRAGS(cb, kk)                                                    \
  {                                                                           \
    const __bf16* As_ = &ldsA[cb][(warp_m * 64 + fr) * 64];                   \
    const __bf16* Bs_ = &ldsB[cb][(warp_n * 64 + fr) * 64];                   \
    const int pg_ = (((kk)*4 + fq) ^ (fr & 7)) * 8;                           \
    _Pragma("unroll") for (int m = 0; m < 4; ++m)                             \
        af[m] = *(const bf16x8*)(As_ + m * 16 * 64 + pg_);                    \
    _Pragma("unroll") for (int n = 0; n < 4; ++n)                             \
        bfv[n] = *(const bf16x8*)(Bs_ + n * 16 * 64 + pg_);                   \
  }

#define SMFMA16(ACC)                                                          \
  {                                                                           \
    __builtin_amdgcn_s_barrier();                                             \
    asm volatile("s_waitcnt lgkmcnt(0)" ::: "memory");                        \
    __builtin_amdgcn_s_setprio(1);                                            \
    _Pragma("unroll") for (int m = 0; m < 4; ++m)                             \
        _Pragma("unroll") for (int n = 0; n < 4; ++n)                         \
            ACC[m][n] = __builtin_amdgcn_mfma_f32_16x16x32_bf16(              \
                af[m], bfv[n], ACC[m][n], 0, 0, 0);                           \
    __builtin_amdgcn_s_setprio(0);                                            \
    __builtin_amdgcn_s_barrier();                                             \
  }

__global__ __launch_bounds__(512, 2) void gemm_scores_kernel(
    const __bf16* __restrict__ xb, const __bf16* __restrict__ mbb,
    __bf16* __restrict__ s1) {
  __shared__ __align__(16) __bf16 ldsA[3][256 * 64];
  __shared__ __align__(16) __bf16 ldsB[3][128 * 64];
  const int tid = threadIdx.x;
  const int lane = tid & 63;
  const int wave = tid >> 6;
  const int bid = blockIdx.x;            // 256 blocks
  const int xcd = bid & 7;
  const int idx = bid >> 3;              // 0..31
  const int bm = xcd * 8 + (idx & 7);    // 0..63
  const int bn = idx >> 3;               // 0..3
  const int row0 = bm * 256;
  const int col0 = bn * 128;
  const int warp_m = wave >> 1;
  const int warp_n = wave & 1;
  const int srow = lane >> 3;
  const int sgc = (lane & 7) ^ srow;
  const int wv32 = wave * 32;
  const int wv16 = wave * 16;
  const int fr = lane & 15;
  const int fq = lane >> 4;

  const __bf16* aS = xb + (size_t)(row0 + wv32 + srow) * EMBED + sgc * 8;
  const __bf16* bS = mbb + (size_t)(col0 + wv16 + srow) * EMBED + sgc * 8;

#define STAGE_S1(vt, buf)                                                     \
  {                                                                           \
    const int k0_ = (vt)*64;                                                  \
    _Pragma("unroll") for (int c = 0; c < 2; ++c)                             \
        GLDS(aS + (size_t)c * 8 * EMBED + k0_, &ldsA[buf][(wv32 + c * 8) * 64]); \
    GLDS(bS + k0_, &ldsB[buf][wv16 * 64]);                                    \
  }
#define STAGE_S2(vt, buf)                                                     \
  {                                                                           \
    const int k0_ = (vt)*64;                                                  \
    _Pragma("unroll") for (int c = 2; c < 4; ++c)                             \
        GLDS(aS + (size_t)c * 8 * EMBED + k0_, &ldsA[buf][(wv32 + c * 8) * 64]); \
    GLDS(bS + (size_t)8 * EMBED + k0_, &ldsB[buf][(wv16 + 8) * 64]);          \
  }

  f32x4 acc[4][4];
#pragma unroll
  for (int m = 0; m < 4; ++m)
#pragma unroll
    for (int n = 0; n < 4; ++n) acc[m][n] = (f32x4){0.f, 0.f, 0.f, 0.f};
  bf16x8 af[4], bfv[4];

  STAGE_S1(0, 0); STAGE_S2(0, 0);
  STAGE_S1(1, 1); STAGE_S2(1, 1);
  asm volatile("s_waitcnt vmcnt(6)" ::: "memory");
  __builtin_amdgcn_s_barrier();

  const int NT = 16;
  for (int vt = 0; vt < NT; ++vt) {
    const int cb = vt % 3;
    const int nb = (vt + 2) % 3;
    SLOADFRAGS(cb, 0);
    if (vt + 2 < NT) STAGE_S1(vt + 2, nb);
    SMFMA16(acc);
    SLOADFRAGS(cb, 1);
    if (vt + 2 < NT) STAGE_S2(vt + 2, nb);
    if (vt < NT - 2) {
      asm volatile("s_waitcnt vmcnt(6)" ::: "memory");
    } else if (vt == NT - 2) {
      asm volatile("s_waitcnt vmcnt(0)" ::: "memory");
    }
    SMFMA16(acc);
  }
#undef STAGE_S1
#undef STAGE_S2

#pragma unroll
  for (int n = 0; n < 4; ++n) {
    const int col = col0 + warp_n * 64 + n * 16 + fr;
#pragma unroll
    for (int m = 0; m < 4; ++m)
#pragma unroll
      for (int j = 0; j < 4; ++j) {
        const int row = row0 + warp_m * 64 + m * 16 + fq * 4 + j;
        s1[(size_t)row * WINDOW + col] = (__bf16)acc[m][n][j];
      }
  }
}

// ======= fused dual GEMM + blend: 4 waves, 128x128, dbuf, 2 blocks/CU ====
// R11's proven kernel verbatim (73 us, MfmaUtil 28%, 0 conflicts):
// BK=64 dbuf, STG -> vmcnt(8) -> bar -> COMPUTE -> bar; 128B-row layout
// with 8-granule involution; bn-inner bijection for A-panel L2 locality.
__global__ __launch_bounds__(256, 2) void dual_fused128_kernel(
    const __bf16* __restrict__ s1, const __bf16* __restrict__ xb,
    const __bf16* __restrict__ mbt, const __bf16* __restrict__ gwb,
    const float* __restrict__ gb, float* __restrict__ out) {
  __shared__ __align__(16) __bf16 ldsA[2][128 * 64];  // 32 KB
  __shared__ __align__(16) __bf16 ldsB[2][128 * 64];  // 32 KB
  const int tid = threadIdx.x, lane = tid & 63, wave = tid >> 6;
  const int bid = blockIdx.x;
  const int xcd = bid & 7;
  const int g = bid >> 3;                  // 0..127
  const int bm = xcd * 16 + (g >> 3);      // bn inner: A-panel L2 locality
  const int bn = g & 7;
  const int row0 = bm * 128, col0 = bn * 128;
  const int warp_m = wave >> 1, warp_n = wave & 1;  // 2x2 waves, 64x64 tiles
  const int fr = lane & 15, fq = lane >> 4;
  const int srow = lane >> 3;              // 0..7
  const int sgc = (lane & 7) ^ srow;       // pre-swizzled source granule
  const int wv32 = wave * 32;

  const __bf16* aR = s1 + (size_t)(row0 + wv32 + srow) * WINDOW + sgc * 8;
  const __bf16* bR = mbt + (size_t)(col0 + wv32 + srow) * WINDOW + sgc * 8;
  const __bf16* aG = xb + (size_t)(row0 + wv32 + srow) * EMBED + sgc * 8;
  const __bf16* bG = gwb + (size_t)(col0 + wv32 + srow) * EMBED + sgc * 8;

#define STG(vt, buf)                                                          \
  {                                                                           \
    if ((vt) < 8) {                                                           \
      const int k0_ = (vt)*64;                                                \
      _Pragma("unroll") for (int c = 0; c < 4; ++c)                           \
          GLDS(aR + (size_t)c * 8 * WINDOW + k0_,                             \
               &ldsA[buf][(wv32 + c * 8) * 64]);                              \
      _Pragma("unroll") for (int c = 0; c < 4; ++c)                           \
          GLDS(bR + (size_t)c * 8 * WINDOW + k0_,                             \
               &ldsB[buf][(wv32 + c * 8) * 64]);                              \
    } else {                                                                  \
      const int k0_ = ((vt)-8) * 64;                                          \
      _Pragma("unroll") for (int c = 0; c < 4; ++c)                           \
          GLDS(aG + (size_t)c * 8 * EMBED + k0_,                              \
               &ldsA[buf][(wv32 + c * 8) * 64]);                              \
      _Pragma("unroll") for (int c = 0; c < 4; ++c)                           \
          GLDS(bG + (size_t)c * 8 * EMBED + k0_,                              \
               &ldsB[buf][(wv32 + c * 8) * 64]);                              \
    }                                                                         \
  }

#define BARF                                                                  \
  {                                                                           \
    asm volatile("" ::: "memory");                                            \
    __builtin_amdgcn_s_barrier();                                             \
    asm volatile("" ::: "memory");                                            \
  }

#define COMPUTE(ACC, cur)                                                     \
  {                                                                           \
    const __bf16* As_ = &ldsA[cur][(warp_m * 64 + fr) * 64];                  \
    const __bf16* Bs_ = &ldsB[cur][(warp_n * 64 + fr) * 64];                  \
    _Pragma("unroll") for (int kk = 0; kk < 2; ++kk) {                        \
      const int pg_ = ((kk * 4 + fq) ^ (fr & 7)) * 8;                         \
      bf16x8 af[4], bfv[4];                                                   \
      _Pragma("unroll") for (int m = 0; m < 4; ++m)                           \
          af[m] = *(const bf16x8*)(As_ + m * 16 * 64 + pg_);                  \
      _Pragma("unroll") for (int n = 0; n < 4; ++n)                           \
          bfv[n] = *(const bf16x8*)(Bs_ + n * 16 * 64 + pg_);                 \
      __builtin_amdgcn_s_setprio(1);                                          \
      _Pragma("unroll") for (int m = 0; m < 4; ++m)                           \
          _Pragma("unroll") for (int n = 0; n < 4; ++n)                       \
              ACC[m][n] = __builtin_amdgcn_mfma_f32_16x16x32_bf16(            \
                  af[m], bfv[n], ACC[m][n], 0, 0, 0);                         \
      __builtin_amdgcn_s_setprio(0);                                          \
    }                                                                         \
  }

  f32x4 accr[4][4], accg[4][4];
#pragma unroll
  for (int m = 0; m < 4; ++m)
#pragma unroll
    for (int n = 0; n < 4; ++n) {
      accr[m][n] = (f32x4){0.f, 0.f, 0.f, 0.f};
      accg[m][n] = (f32x4){0.f, 0.f, 0.f, 0.f};
    }

  STG(0, 0);
  for (int vt = 0; vt < 8; ++vt) {
    const int cur = vt & 1;
    STG(vt + 1, cur ^ 1);
    asm volatile("s_waitcnt vmcnt(8)" ::: "memory");
    BARF;
    COMPUTE(accr, cur);
    BARF;
  }
  for (int vt = 8; vt < 24; ++vt) {
    const int cur = vt & 1;
    if (vt + 1 < 24) {
      STG(vt + 1, cur ^ 1);
      asm volatile("s_waitcnt vmcnt(8)" ::: "memory");
    } else {
      asm volatile("s_waitcnt vmcnt(0)" ::: "memory");
    }
    BARF;
    COMPUTE(accg, cur);
    BARF;
  }
#undef STG
#undef COMPUTE
#undef BARF

#pragma unroll
  for (int n = 0; n < 4; ++n) {
    const int col = col0 + warp_n * 64 + n * 16 + fr;
    const float bias = gb[col];
#pragma unroll
    for (int m = 0; m < 4; ++m) {
#pragma unroll
      for (int j = 0; j < 4; ++j) {
        const int row = row0 + warp_m * 64 + m * 16 + fq * 4 + j;
        const size_t o = (size_t)row * EMBED + col;
        const float gt = 1.0f / (1.0f + __expf(-(accg[m][n][j] + bias)));
        const float xv = (float)xb[o];
        out[o] = gt * xv + (1.0f - gt) * accr[m][n][j];
      }
    }
  }
}

extern "C" void kernel_launch(void* const* d_in, const int* in_sizes, int n_in,
                              void* d_out, int out_size, void* d_ws,
                              size_t ws_size, hipStream_t stream) {
  const float* x = (const float*)d_in[0];
  const float* mb = (const float*)d_in[1];
  const float* gw = (const float*)d_in[2];
  const float* gb = (const float*)d_in[3];
  float* out = (float*)d_out;

  char* ws = (char*)d_ws;
  __bf16* xb = (__bf16*)(ws);                   // 16384*1024*2 = 33,554,432
  __bf16* mbb = (__bf16*)(ws + 33554432);       // 512*1024*2  =  1,048,576
  __bf16* mbt = (__bf16*)(ws + 34603008);       // 1024*512*2  =  1,048,576
  __bf16* gwb = (__bf16*)(ws + 35651584);       // 1024*1024*2 =  2,097,152
  __bf16* s1 = (__bf16*)(ws + 37748736);        // 16384*512*2 = 16,777,216
  // total 54,525,952 bytes

  cast_bf16_kernel<<<8192, 256, 0, stream>>>(x, xb, 2097152);
  cast_bf16_kernel<<<256, 256, 0, stream>>>(mb, mbb, 65536);
  cast_bf16_kernel<<<512, 256, 0, stream>>>(gw, gwb, 131072);
  transpose_mb_lds_kernel<<<512, 256, 0, stream>>>(mb, mbt);
  gemm_scores_kernel<<<256, 512, 0, stream>>>(xb, mbb, s1);
  softmax_kernel<<<4096, 256, 0, stream>>>(s1);
  dual_fused128_kernel<<<1024, 256, 0, stream>>>(s1, xb, mbt, gwb, gb, out);
}

// Round 21
// 115.669 us; speedup vs baseline: 1.7068x; 1.0102x over previous
//
#include <hip/hip_runtime.h>
#include <hip/hip_bf16.h>

#define EMBED 1024
#define WINDOW 512
#define NROWS 16384  // 4 * 4096

typedef __attribute__((ext_vector_type(4))) float f32x4;
typedef __bf16 bf16x8 __attribute__((ext_vector_type(8)));

#define GLDS(g, l)                                                        \
  __builtin_amdgcn_global_load_lds(                                       \
      (const __attribute__((address_space(1))) void*)(const void*)(g),    \
      (__attribute__((address_space(3))) void*)(void*)(l), 16, 0, 0)

static __device__ __forceinline__ unsigned bfb(float v) {
  return (unsigned)__builtin_bit_cast(unsigned short, (__bf16)v);
}

// ---------------- prep: fp32 -> bf16 cast, 8 elems/thread ----------------
__global__ __launch_bounds__(256) void cast_bf16_kernel(
    const float* __restrict__ in, __bf16* __restrict__ out, int n8) {
  int i = blockIdx.x * blockDim.x + threadIdx.x;
  if (i >= n8) return;
  const f32x4* p = (const f32x4*)(in + (size_t)i * 8);
  f32x4 a = p[0], b = p[1];
  bf16x8 o = {(__bf16)a[0], (__bf16)a[1], (__bf16)a[2], (__bf16)a[3],
              (__bf16)b[0], (__bf16)b[1], (__bf16)b[2], (__bf16)b[3]};
  *(bf16x8*)(out + (size_t)i * 8) = o;
}

// ----- prep: MB [512][1024] f32 -> mbb (bf16 row-major) + mbt (bf16 T) ---
// 32x32 tiles; coalesced f32x4 read, coalesced uint2 writes for both outs.
__global__ __launch_bounds__(256) void prep_mb_kernel(
    const float* __restrict__ mb, __bf16* __restrict__ mbb,
    __bf16* __restrict__ mbt) {
  __shared__ __bf16 tile[32][33];
  const int tx = threadIdx.x & 7, ty = threadIdx.x >> 3;  // 8 x 32
  const int w0 = (blockIdx.x & 15) * 32;   // 512/32 = 16
  const int d0 = (blockIdx.x >> 4) * 32;   // 1024/32 = 32 -> 512 blocks
  f32x4 v = *(const f32x4*)(mb + (size_t)(w0 + ty) * EMBED + d0 + tx * 4);
  // row-major bf16 copy (mbb)
  {
    unsigned u0 = (bfb(v[1]) << 16) | bfb(v[0]);
    unsigned u1 = (bfb(v[3]) << 16) | bfb(v[2]);
    uint2 w2 = {u0, u1};
    *(uint2*)(mbb + (size_t)(w0 + ty) * EMBED + d0 + tx * 4) = w2;
  }
#pragma unroll
  for (int j = 0; j < 4; ++j) tile[tx * 4 + j][ty] = (__bf16)v[j];
  __syncthreads();
  unsigned u0 = (bfb((float)tile[ty][tx * 4 + 1]) << 16) |
                bfb((float)tile[ty][tx * 4 + 0]);
  unsigned u1 = (bfb((float)tile[ty][tx * 4 + 3]) << 16) |
                bfb((float)tile[ty][tx * 4 + 2]);
  uint2 w2 = {u0, u1};
  *(uint2*)(mbt + (size_t)(d0 + ty) * WINDOW + w0 + tx * 4) = w2;
}

// ---------------- softmax in-place on S1 rows (512 wide) -----------------
__global__ __launch_bounds__(256) void softmax_kernel(__bf16* __restrict__ s1) {
  const int row = blockIdx.x * 4 + (threadIdx.x >> 6);
  const int lane = threadIdx.x & 63;
  __bf16* p = s1 + (size_t)row * WINDOW + lane * 8;
  bf16x8 v = *(const bf16x8*)p;
  float f[8];
  float mx = -1e30f;
#pragma unroll
  for (int j = 0; j < 8; ++j) {
    f[j] = (float)v[j] * 0.03125f;  // 1/sqrt(1024)
    mx = fmaxf(mx, f[j]);
  }
#pragma unroll
  for (int off = 1; off < 64; off <<= 1) mx = fmaxf(mx, __shfl_xor(mx, off));
  float s = 0.f;
#pragma unroll
  for (int j = 0; j < 8; ++j) {
    f[j] = __expf(f[j] - mx);
    s += f[j];
  }
#pragma unroll
  for (int off = 1; off < 64; off <<= 1) s += __shfl_xor(s, off);
  const float inv = 1.0f / s;
  bf16x8 o;
#pragma unroll
  for (int j = 0; j < 8; ++j) o[j] = (__bf16)(f[j] * inv);
  *(bf16x8*)p = o;
}

// ---------------- scores kernel (R5 structure, known-good) ---------------
#define SLOADFRAGS(cb, kk)                                                    \
  {                                                                           \
    const __bf16* As_ = &ldsA[cb][(warp_m * 64 + fr) * 64];                   \
    const __bf16* Bs_ = &ldsB[cb][(warp_n * 64 + fr) * 64];                   \
    const int pg_ = (((kk)*4 + fq) ^ (fr & 7)) * 8;                           \
    _Pragma("unroll") for (int m = 0; m < 4; ++m)                             \
        af[m] = *(const bf16x8*)(As_ + m * 16 * 64 + pg_);                    \
    _Pragma("unroll") for (int n = 0; n < 4; ++n)                             \
        bfv[n] = *(const bf16x8*)(Bs_ + n * 16 * 64 + pg_);                   \
  }

#define SMFMA16(ACC)                                                          \
  {                                                                           \
    __builtin_amdgcn_s_barrier();                                             \
    asm volatile("s_waitcnt lgkmcnt(0)" ::: "memory");                        \
    __builtin_amdgcn_s_setprio(1);                                            \
    _Pragma("unroll") for (int m = 0; m < 4; ++m)                             \
        _Pragma("unroll") for (int n = 0; n < 4; ++n)                         \
            ACC[m][n] = __builtin_amdgcn_mfma_f32_16x16x32_bf16(              \
                af[m], bfv[n], ACC[m][n], 0, 0, 0);                           \
    __builtin_amdgcn_s_setprio(0);                                            \
    __builtin_amdgcn_s_barrier();                                             \
  }

__global__ __launch_bounds__(512, 2) void gemm_scores_kernel(
    const __bf16* __restrict__ xb, const __bf16* __restrict__ mbb,
    __bf16* __restrict__ s1) {
  __shared__ __align__(16) __bf16 ldsA[3][256 * 64];
  __shared__ __align__(16) __bf16 ldsB[3][128 * 64];
  const int tid = threadIdx.x;
  const int lane = tid & 63;
  const int wave = tid >> 6;
  const int bid = blockIdx.x;            // 256 blocks
  const int xcd = bid & 7;
  const int idx = bid >> 3;              // 0..31
  const int bm = xcd * 8 + (idx & 7);    // 0..63
  const int bn = idx >> 3;               // 0..3
  const int row0 = bm * 256;
  const int col0 = bn * 128;
  const int warp_m = wave >> 1;
  const int warp_n = wave & 1;
  const int srow = lane >> 3;
  const int sgc = (lane & 7) ^ srow;
  const int wv32 = wave * 32;
  const int wv16 = wave * 16;
  const int fr = lane & 15;
  const int fq = lane >> 4;

  const __bf16* aS = xb + (size_t)(row0 + wv32 + srow) * EMBED + sgc * 8;
  const __bf16* bS = mbb + (size_t)(col0 + wv16 + srow) * EMBED + sgc * 8;

#define STAGE_S1(vt, buf)                                                     \
  {                                                                           \
    const int k0_ = (vt)*64;                                                  \
    _Pragma("unroll") for (int c = 0; c < 2; ++c)                             \
        GLDS(aS + (size_t)c * 8 * EMBED + k0_, &ldsA[buf][(wv32 + c * 8) * 64]); \
    GLDS(bS + k0_, &ldsB[buf][wv16 * 64]);                                    \
  }
#define STAGE_S2(vt, buf)                                                     \
  {                                                                           \
    const int k0_ = (vt)*64;                                                  \
    _Pragma("unroll") for (int c = 2; c < 4; ++c)                             \
        GLDS(aS + (size_t)c * 8 * EMBED + k0_, &ldsA[buf][(wv32 + c * 8) * 64]); \
    GLDS(bS + (size_t)8 * EMBED + k0_, &ldsB[buf][(wv16 + 8) * 64]);          \
  }

  f32x4 acc[4][4];
#pragma unroll
  for (int m = 0; m < 4; ++m)
#pragma unroll
    for (int n = 0; n < 4; ++n) acc[m][n] = (f32x4){0.f, 0.f, 0.f, 0.f};
  bf16x8 af[4], bfv[4];

  STAGE_S1(0, 0); STAGE_S2(0, 0);
  STAGE_S1(1, 1); STAGE_S2(1, 1);
  asm volatile("s_waitcnt vmcnt(6)" ::: "memory");
  __builtin_amdgcn_s_barrier();

  const int NT = 16;
  for (int vt = 0; vt < NT; ++vt) {
    const int cb = vt % 3;
    const int nb = (vt + 2) % 3;
    SLOADFRAGS(cb, 0);
    if (vt + 2 < NT) STAGE_S1(vt + 2, nb);
    SMFMA16(acc);
    SLOADFRAGS(cb, 1);
    if (vt + 2 < NT) STAGE_S2(vt + 2, nb);
    if (vt < NT - 2) {
      asm volatile("s_waitcnt vmcnt(6)" ::: "memory");
    } else if (vt == NT - 2) {
      asm volatile("s_waitcnt vmcnt(0)" ::: "memory");
    }
    SMFMA16(acc);
  }
#undef STAGE_S1
#undef STAGE_S2

#pragma unroll
  for (int n = 0; n < 4; ++n) {
    const int col = col0 + warp_n * 64 + n * 16 + fr;
#pragma unroll
    for (int m = 0; m < 4; ++m)
#pragma unroll
      for (int j = 0; j < 4; ++j) {
        const int row = row0 + warp_m * 64 + m * 16 + fq * 4 + j;
        s1[(size_t)row * WINDOW + col] = (__bf16)acc[m][n][j];
      }
  }
}

// ======= fused dual GEMM + blend: 4 waves, 128x128, dbuf, 2 blocks/CU ====
// R11's proven kernel verbatim (73 us, MfmaUtil 28%, 0 conflicts):
// BK=64 dbuf, STG -> vmcnt(8) -> bar -> COMPUTE -> bar; 128B-row layout
// with 8-granule involution; bn-inner bijection for A-panel L2 locality.
__global__ __launch_bounds__(256, 2) void dual_fused128_kernel(
    const __bf16* __restrict__ s1, const __bf16* __restrict__ xb,
    const __bf16* __restrict__ mbt, const __bf16* __restrict__ gwb,
    const float* __restrict__ gb, float* __restrict__ out) {
  __shared__ __align__(16) __bf16 ldsA[2][128 * 64];  // 32 KB
  __shared__ __align__(16) __bf16 ldsB[2][128 * 64];  // 32 KB
  const int tid = threadIdx.x, lane = tid & 63, wave = tid >> 6;
  const int bid = blockIdx.x;
  const int xcd = bid & 7;
  const int g = bid >> 3;                  // 0..127
  const int bm = xcd * 16 + (g >> 3);      // bn inner: A-panel L2 locality
  const int bn = g & 7;
  const int row0 = bm * 128, col0 = bn * 128;
  const int warp_m = wave >> 1, warp_n = wave & 1;  // 2x2 waves, 64x64 tiles
  const int fr = lane & 15, fq = lane >> 4;
  const int srow = lane >> 3;              // 0..7
  const int sgc = (lane & 7) ^ srow;       // pre-swizzled source granule
  const int wv32 = wave * 32;

  const __bf16* aR = s1 + (size_t)(row0 + wv32 + srow) * WINDOW + sgc * 8;
  const __bf16* bR = mbt + (size_t)(col0 + wv32 + srow) * WINDOW + sgc * 8;
  const __bf16* aG = xb + (size_t)(row0 + wv32 + srow) * EMBED + sgc * 8;
  const __bf16* bG = gwb + (size_t)(col0 + wv32 + srow) * EMBED + sgc * 8;

#define STG(vt, buf)                                                          \
  {                                                                           \
    if ((vt) < 8) {                                                           \
      const int k0_ = (vt)*64;                                                \
      _Pragma("unroll") for (int c = 0; c < 4; ++c)                           \
          GLDS(aR + (size_t)c * 8 * WINDOW + k0_,                             \
               &ldsA[buf][(wv32 + c * 8) * 64]);                              \
      _Pragma("unroll") for (int c = 0; c < 4; ++c)                           \
          GLDS(bR + (size_t)c * 8 * WINDOW + k0_,                             \
               &ldsB[buf][(wv32 + c * 8) * 64]);                              \
    } else {                                                                  \
      const int k0_ = ((vt)-8) * 64;                                          \
      _Pragma("unroll") for (int c = 0; c < 4; ++c)                           \
          GLDS(aG + (size_t)c * 8 * EMBED + k0_,                              \
               &ldsA[buf][(wv32 + c * 8) * 64]);                              \
      _Pragma("unroll") for (int c = 0; c < 4; ++c)                           \
          GLDS(bG + (size_t)c * 8 * EMBED + k0_,                              \
               &ldsB[buf][(wv32 + c * 8) * 64]);                              \
    }                                                                         \
  }

#define BARF                                                                  \
  {                                                                           \
    asm volatile("" ::: "memory");                                            \
    __builtin_amdgcn_s_barrier();                                             \
    asm volatile("" ::: "memory");                                            \
  }

#define COMPUTE(ACC, cur)                                                     \
  {                                                                           \
    const __bf16* As_ = &ldsA[cur][(warp_m * 64 + fr) * 64];                  \
    const __bf16* Bs_ = &ldsB[cur][(warp_n * 64 + fr) * 64];                  \
    _Pragma("unroll") for (int kk = 0; kk < 2; ++kk) {                        \
      const int pg_ = ((kk * 4 + fq) ^ (fr & 7)) * 8;                         \
      bf16x8 af[4], bfv[4];                                                   \
      _Pragma("unroll") for (int m = 0; m < 4; ++m)                           \
          af[m] = *(const bf16x8*)(As_ + m * 16 * 64 + pg_);                  \
      _Pragma("unroll") for (int n = 0; n < 4; ++n)                           \
          bfv[n] = *(const bf16x8*)(Bs_ + n * 16 * 64 + pg_);                 \
      __builtin_amdgcn_s_setprio(1);                                          \
      _Pragma("unroll") for (int m = 0; m < 4; ++m)                           \
          _Pragma("unroll") for (int n = 0; n < 4; ++n)                       \
              ACC[m][n] = __builtin_amdgcn_mfma_f32_16x16x32_bf16(            \
                  af[m], bfv[n], ACC[m][n], 0, 0, 0);                         \
      __builtin_amdgcn_s_setprio(0);                                          \
    }                                                                         \
  }

  f32x4 accr[4][4], accg[4][4];
#pragma unroll
  for (int m = 0; m < 4; ++m)
#pragma unroll
    for (int n = 0; n < 4; ++n) {
      accr[m][n] = (f32x4){0.f, 0.f, 0.f, 0.f};
      accg[m][n] = (f32x4){0.f, 0.f, 0.f, 0.f};
    }

  STG(0, 0);
  for (int vt = 0; vt < 8; ++vt) {
    const int cur = vt & 1;
    STG(vt + 1, cur ^ 1);
    asm volatile("s_waitcnt vmcnt(8)" ::: "memory");
    BARF;
    COMPUTE(accr, cur);
    BARF;
  }
  for (int vt = 8; vt < 24; ++vt) {
    const int cur = vt & 1;
    if (vt + 1 < 24) {
      STG(vt + 1, cur ^ 1);
      asm volatile("s_waitcnt vmcnt(8)" ::: "memory");
    } else {
      asm volatile("s_waitcnt vmcnt(0)" ::: "memory");
    }
    BARF;
    COMPUTE(accg, cur);
    BARF;
  }
#undef STG
#undef COMPUTE
#undef BARF

#pragma unroll
  for (int n = 0; n < 4; ++n) {
    const int col = col0 + warp_n * 64 + n * 16 + fr;
    const float bias = gb[col];
#pragma unroll
    for (int m = 0; m < 4; ++m) {
#pragma unroll
      for (int j = 0; j < 4; ++j) {
        const int row = row0 + warp_m * 64 + m * 16 + fq * 4 + j;
        const size_t o = (size_t)row * EMBED + col;
        const float gt = 1.0f / (1.0f + __expf(-(accg[m][n][j] + bias)));
        const float xv = (float)xb[o];
        out[o] = gt * xv + (1.0f - gt) * accr[m][n][j];
      }
    }
  }
}

extern "C" void kernel_launch(void* const* d_in, const int* in_sizes, int n_in,
                              void* d_out, int out_size, void* d_ws,
                              size_t ws_size, hipStream_t stream) {
  const float* x = (const float*)d_in[0];
  const float* mb = (const float*)d_in[1];
  const float* gw = (const float*)d_in[2];
  const float* gb = (const float*)d_in[3];
  float* out = (float*)d_out;

  char* ws = (char*)d_ws;
  __bf16* xb = (__bf16*)(ws);                   // 16384*1024*2 = 33,554,432
  __bf16* mbb = (__bf16*)(ws + 33554432);       // 512*1024*2  =  1,048,576
  __bf16* mbt = (__bf16*)(ws + 34603008);       // 1024*512*2  =  1,048,576
  __bf16* gwb = (__bf16*)(ws + 35651584);       // 1024*1024*2 =  2,097,152
  __bf16* s1 = (__bf16*)(ws + 37748736);        // 16384*512*2 = 16,777,216
  // total 54,525,952 bytes

  cast_bf16_kernel<<<8192, 256, 0, stream>>>(x, xb, 2097152);
  cast_bf16_kernel<<<512, 256, 0, stream>>>(gw, gwb, 131072);
  prep_mb_kernel<<<512, 256, 0, stream>>>(mb, mbb, mbt);  // mbb + mbt fused
  gemm_scores_kernel<<<256, 512, 0, stream>>>(xb, mbb, s1);
  softmax_kernel<<<4096, 256, 0, stream>>>(s1);
  dual_fused128_kernel<<<1024, 256, 0, stream>>>(s1, xb, mbt, gwb, gb, out);
}